// Round 4
// baseline (588.210 us; speedup 1.0000x reference)
//
#include <hip/hip_runtime.h>
#include <math.h>

#define N 8192
#define IN_F 512
#define OUTF 64
#define TI 16
#define JT 256               // j-cols per tile
#define NTILE (N / JT)       // 32 phases
#define PS 264               // P_lds row stride (f16)
#define MROW 1024            // mask bytes per row (8192/8)

typedef _Float16 f16x8 __attribute__((ext_vector_type(8)));
typedef float f32x4 __attribute__((ext_vector_type(4)));
typedef int i32x4 __attribute__((ext_vector_type(4)));

// workspace layout (floats) — ~9.2 MB
#define OFF_HT   0u          // hT: 64x8192 f16 = 262144 float-slots
#define OFF_S    262144u     // s2 = |W_ei| * (h@a1)
#define OFF_T    270336u     // t2 = |W_ei| * (h@a2)
#define OFF_TMAX 278528u     // 16
#define OFF_MASK 294912u     // 8 MB bitmask: [8192][1024] bytes

#define SB0() __builtin_amdgcn_sched_barrier(0)
#define SYNC()                                           \
  SB0();                                                 \
  asm volatile("s_waitcnt lgkmcnt(0)" ::: "memory");     \
  SB0();                                                 \
  __builtin_amdgcn_s_barrier();                          \
  SB0();

__device__ __forceinline__ unsigned enc_f32(float f) {
  unsigned b = __float_as_uint(f);
  return b ^ ((unsigned)((int)b >> 31) | 0x80000000u);
}

// ---------------------------------------------------------------------------
// K1 (fused): per block —
//   GEMM part: hT[f][j]=(f16)(input@W)[j][f]; s2=aei*(h@a1); t2=aei*(h@a2);
//              one atomicMax(tmax) per block (replaces k_tmax).
//   MASK part: grid-stride adj -> 1-bit/elem mask, NONTEMPORAL adj reads
//              (keeps L3 free for adj_ad, which k_attn wants resident).
// Parity-swapped section order so ~half the waves stream while half GEMM.
// ---------------------------------------------------------------------------
__global__ __launch_bounds__(64) void k_precompute(
    const float* __restrict__ input, const float* __restrict__ W,
    const float* __restrict__ a, const float* __restrict__ W_ei,
    const int* __restrict__ adj, _Float16* __restrict__ hT,
    float* __restrict__ s2, float* __restrict__ t2,
    unsigned* __restrict__ tmax, unsigned char* __restrict__ mask) {
  const int lane = threadIdx.x;
  const int i0 = blockIdx.x * 4;
  const float aei = fabsf(W_ei[0]);

  auto GEMM = [&]() {
    float acc[4] = {0.f, 0.f, 0.f, 0.f};
    for (int c = 0; c < IN_F; c += 4) {
      const float w0 = W[(c + 0) * OUTF + lane];
      const float w1 = W[(c + 1) * OUTF + lane];
      const float w2 = W[(c + 2) * OUTF + lane];
      const float w3 = W[(c + 3) * OUTF + lane];
      #pragma unroll
      for (int r = 0; r < 4; r++) {
        const float4 iv = *(const float4*)(input + (size_t)(i0 + r) * IN_F + c);
        acc[r] += iv.x * w0 + iv.y * w1 + iv.z * w2 + iv.w * w3;
      }
    }

    union { _Float16 f[4]; uint2 u; } pk;
    #pragma unroll
    for (int r = 0; r < 4; r++) pk.f[r] = (_Float16)acc[r];
    *(uint2*)(hT + (size_t)lane * N + i0) = pk.u;

    const float a1v = a[lane];
    const float a2v = a[OUTF + lane];
    float tloc = -1e30f;
    #pragma unroll
    for (int r = 0; r < 4; r++) {
      float sv = acc[r] * a1v;
      float tv = acc[r] * a2v;
      #pragma unroll
      for (int off = 1; off < 64; off <<= 1) {
        sv += __shfl_xor(sv, off);
        tv += __shfl_xor(tv, off);
      }
      if (lane == 0) {
        s2[i0 + r] = aei * sv;
        const float t2v = aei * tv;
        t2[i0 + r] = t2v;
        tloc = fmaxf(tloc, t2v);
      }
    }
    if (lane == 0) atomicMax(tmax, enc_f32(tloc));
  };

  auto MASK = [&]() {
    const unsigned gtid = blockIdx.x * 64 + lane;   // 0..131071
    #pragma unroll 1
    for (int o = 0; o < 64; o += 4) {
      i32x4 v[4][2];
      #pragma unroll
      for (int u = 0; u < 4; u++) {
        const size_t B = gtid + (size_t)(o + u) * 131072;  // byte index
        const i32x4* p = (const i32x4*)adj + B * 2;        // addr = adj+8B
        v[u][0] = __builtin_nontemporal_load(p);
        v[u][1] = __builtin_nontemporal_load(p + 1);
      }
      #pragma unroll
      for (int u = 0; u < 4; u++) {
        const size_t B = gtid + (size_t)(o + u) * 131072;
        const unsigned b = (unsigned)(v[u][0].x > 0) |
                           ((unsigned)(v[u][0].y > 0) << 1) |
                           ((unsigned)(v[u][0].z > 0) << 2) |
                           ((unsigned)(v[u][0].w > 0) << 3) |
                           ((unsigned)(v[u][1].x > 0) << 4) |
                           ((unsigned)(v[u][1].y > 0) << 5) |
                           ((unsigned)(v[u][1].z > 0) << 6) |
                           ((unsigned)(v[u][1].w > 0) << 7);
        mask[B] = (unsigned char)b;
      }
    }
  };

  if (blockIdx.x & 1) { MASK(); GEMM(); }
  else                { GEMM(); MASK(); }
}

// ---------------------------------------------------------------------------
// K2 v5: v4's reg-direct pipeline, but adj(256MB int32) replaced by an 8MB
// bitmask -> k_attn working set = adj_ad(268MB)+mask(8MB) ~= L3 capacity.
// Cross-iteration L3 retention (proven by R2's FETCH 271MB < 512MB reads and
// fills not evicting) should now serve ~90% of adj_ad from L3.
// Lane cols contiguous (c0=cw*8): 1KB contiguous per half-wave per load pair,
// one mask byte per lane, one 16B LDS P-write. Pipeline/sync unchanged (T4:
// prefetch rides across raw s_barrier; SYNC waits lgkm only).
// ---------------------------------------------------------------------------
__global__ __launch_bounds__(512, 4) void k_attn(
    const _Float16* __restrict__ hT, const float* __restrict__ s2,
    const float* __restrict__ t2, const unsigned* __restrict__ tmaxp,
    const float* __restrict__ W_si, const unsigned char* __restrict__ mask,
    const float* __restrict__ adj_ad, float* __restrict__ out) {
  __shared__ __align__(16) float smem[8224];   // 32896 B
  _Float16* P = (_Float16*)smem;               // [2][16][PS] f16 = 16896 B

  const int tid = threadIdx.x;
  const int w = tid >> 6;          // wave 0..7
  const int lane = tid & 63;
  const int q = lane >> 4;
  const int m = lane & 15;
  const int h2 = lane >> 5;        // half-wave -> row parity
  const int cw = lane & 31;        // col-lane within half
  const int i0 = blockIdx.x * TI;

  const float asi = fabsf(W_si[0]);
  const unsigned te = *tmaxp;
  const float tm2 = __uint_as_float((te & 0x80000000u) ? (te ^ 0x80000000u) : ~te);

  const int myrow = 2 * w + h2;
  const float s2r = s2[i0 + myrow];
  const float ym = s2r + tm2;
  const float MrB = fmaxf(ym, 0.2f * ym) + asi;   // row upper bound on e

  float S = 0.f;
  f32x4 acc[4];
  #pragma unroll
  for (int nb = 0; nb < 4; nb++) acc[nb] = (f32x4){0.f, 0.f, 0.f, 0.f};

  const size_t gRow = (size_t)(i0 + myrow) * N;
  const unsigned char* mrow = mask + (size_t)(i0 + myrow) * MROW;
  const int c0 = cw * 8;           // 8 contiguous cols per lane

  struct PF { float4 a0, a1; unsigned mb; };

  auto LOADT = [&](int kt) -> PF {
    const size_t b = gRow + (size_t)kt * JT + c0;
    PF p;
    p.a0 = *(const float4*)(adj_ad + b);
    p.a1 = *(const float4*)(adj_ad + b + 4);
    p.mb = mrow[kt * 32 + cw];     // bit e = col c0+e
    return p;
  };

  auto EXPW = [&](int kt, const PF& p, const float4& tva, const float4& tvb) {
    const float ad[8] = {p.a0.x, p.a0.y, p.a0.z, p.a0.w,
                         p.a1.x, p.a1.y, p.a1.z, p.a1.w};
    const float tv[8] = {tva.x, tva.y, tva.z, tva.w,
                         tvb.x, tvb.y, tvb.z, tvb.w};
    union { _Float16 hh[8]; uint4 u4; } pk;
    #pragma unroll
    for (int e = 0; e < 8; e++) {
      const float y = s2r + tv[e];
      const float lr = fmaxf(y, 0.2f * y);
      const float arg = fmaf(asi, ad[e], lr - MrB);          // <= 0 always
      const float pv = ((p.mb >> e) & 1u) ? __expf(arg) : 0.f;
      S += pv;
      pk.hh[e] = (_Float16)pv;
    }
    _Float16* dst = P + (kt & 1) * (16 * PS) + myrow * PS;
    *(uint4*)(dst + c0) = pk.u4;   // one 16B write, 512B contig per half-wave
  };

  #define MLOAD(kt, FB, FA)                                                   \
    {                                                                         \
      const int cb_ = (kt) * JT + w * 32 + q * 8;                             \
      _Pragma("unroll") for (int nb = 0; nb < 4; nb++)                        \
          FB[nb] = *(const f16x8*)(hT + (size_t)(nb * 16 + m) * N + cb_);     \
      FA = *(const f16x8*)(P + ((kt) & 1) * (16 * PS) + m * PS + w * 32 +     \
                           q * 8);                                            \
    }

  #define MSTEP(FB, FA)                                                       \
    {                                                                         \
      _Pragma("unroll") for (int nb = 0; nb < 4; nb++)                        \
          acc[nb] = __builtin_amdgcn_mfma_f32_16x16x32_f16(FA, FB[nb],        \
                                                           acc[nb], 0, 0, 0);\
    }

  PF pA = LOADT(0);
  PF pB;

  #pragma unroll 1
  for (int k = 0; k < NTILE; k += 2) {
    // ---- sub-phase A: MFMA(k-1); exp(k) from pA; prefetch k+1 -> pB ----
    {
      const float4 tva = *(const float4*)(t2 + k * JT + c0);
      const float4 tvb = *(const float4*)(t2 + k * JT + c0 + 4);
      f16x8 fb[4], fa;
      if (k >= 1) MLOAD(k - 1, fb, fa);
      SB0();
      pB = LOADT(k + 1);             // prefetch, stays in flight
      SB0();
      if (k >= 1) MSTEP(fb, fa);     // fb wait leaves newest (pB) in flight
      EXPW(k, pA, tva, tvb);         // pA is oldest -> already drained
      SYNC();
    }
    // ---- sub-phase B: MFMA(k); exp(k+1) from pB; prefetch k+2 -> pA ----
    {
      const float4 tva = *(const float4*)(t2 + (k + 1) * JT + c0);
      const float4 tvb = *(const float4*)(t2 + (k + 1) * JT + c0 + 4);
      f16x8 fb[4], fa;
      MLOAD(k, fb, fa);
      SB0();
      if (k + 2 < NTILE) pA = LOADT(k + 2);
      SB0();
      MSTEP(fb, fa);
      EXPW(k + 1, pB, tva, tvb);
      SYNC();
    }
  }

  // trailing MFMA for tile NTILE-1
  {
    f16x8 fb[4], fa;
    MLOAD(NTILE - 1, fb, fa);
    MSTEP(fb, fa);
  }

  // row-sum S within half-wave (32 lanes cover one row)
  #pragma unroll
  for (int off = 1; off < 32; off <<= 1) S += __shfl_xor(S, off);

  SYNC();   // all P reads complete before smem is repurposed

  // ---- epilogue: cross-wave reduce in LDS ----
  if ((lane & 31) == 0) smem[8192 + myrow] = S;
  #pragma unroll
  for (int nb = 0; nb < 4; nb++) {
    #pragma unroll
    for (int reg = 0; reg < 4; reg++) {
      smem[w * 1024 + (q * 4 + reg) * 64 + nb * 16 + m] = acc[nb][reg];
    }
  }
  __syncthreads();

  #pragma unroll
  for (int ii = 0; ii < 2; ii++) {
    const int e = tid + 512 * ii;
    const int r = e >> 6;
    const int f = e & 63;
    float num = 0.f;
    #pragma unroll
    for (int ww = 0; ww < 8; ww++) num += smem[ww * 1024 + r * 64 + f];
    const float den = smem[8192 + r];
    const float x = num / den;
    out[(size_t)(i0 + r) * OUTF + f] = x > 0.f ? x : expm1f(x);
  }
}

// ---------------------------------------------------------------------------
extern "C" void kernel_launch(void* const* d_in, const int* in_sizes, int n_in,
                              void* d_out, int out_size, void* d_ws, size_t ws_size,
                              hipStream_t stream) {
  const float* input  = (const float*)d_in[0];
  const float* W      = (const float*)d_in[1];
  const float* a      = (const float*)d_in[2];
  const float* W_si   = (const float*)d_in[3];
  const float* W_ei   = (const float*)d_in[4];
  const float* adj_ad = (const float*)d_in[5];
  const int*   adj    = (const int*)d_in[6];
  float* out = (float*)d_out;
  float* ws  = (float*)d_ws;

  _Float16* hT        = (_Float16*)(ws + OFF_HT);
  float* s2           = ws + OFF_S;
  float* t2           = ws + OFF_T;
  unsigned* tmax      = (unsigned*)(ws + OFF_TMAX);
  unsigned char* mask = (unsigned char*)(ws + OFF_MASK);

  hipMemsetAsync(tmax, 0, 4, stream);
  k_precompute<<<N / 4, 64, 0, stream>>>(input, W, a, W_ei, adj, hT, s2, t2,
                                         tmax, mask);
  k_attn<<<N / TI, 512, 0, stream>>>(hT, s2, t2, tmax, W_si, mask,
                                     adj_ad, out);
}